// Round 3
// baseline (2595.334 us; speedup 1.0000x reference)
//
#include <hip/hip_runtime.h>
#include <cmath>

#define BATCH 2
#define HH 256
#define WW 256
#define CDIM 512
#define NHEADS 8
#define NTOK (HH*WW)          // 65536
#define MROWS (BATCH*NTOK)    // 131072

typedef __attribute__((ext_vector_type(8))) short short8v;   // 8 bf16 (4 VGPR)
typedef __attribute__((ext_vector_type(4))) float f32x4;     // MFMA acc

// split helpers: x = hi + lo, hi = truncate-to-bf16, lo = RNE-bf16(x - hi)
__device__ __forceinline__ unsigned int hi_bits(float x) {
    return __float_as_uint(x) & 0xFFFF0000u;            // bf16 in TOP 16 bits
}
__device__ __forceinline__ unsigned int lo_rbits(float x, unsigned int hb) {
    float s = x - __uint_as_float(hb);                  // exact (low mantissa bits)
    unsigned int v = __float_as_uint(s);
    return v + 0x7FFFu + ((v >> 16) & 1u);              // RNE; bf16 = top 16 bits
}

// ---------------------------------------------------------------------------
// Split + transpose weights via LDS tile: W[k][n] f32 -> Wt{hi,lo}[n*512+k] bf16
// grid (8 k-tiles, 8 n-tiles, 4 matrices), 256 thr. Coalesced both sides.
// ---------------------------------------------------------------------------
__global__ __launch_bounds__(256)
void wsplit(const float* __restrict__ w0, const float* __restrict__ w1,
            const float* __restrict__ w2, const float* __restrict__ w3,
            unsigned short* __restrict__ Whi, unsigned short* __restrict__ Wlo)
{
    __shared__ float T[64][65];
    const int m = blockIdx.z;
    const float* src = (m == 0) ? w0 : (m == 1) ? w1 : (m == 2) ? w2 : w3;
    const int k0 = blockIdx.x * 64;     // source row block
    const int n0 = blockIdx.y * 64;     // source col block
    const int r  = threadIdx.x >> 2;    // 0..63
    const int c0 = (threadIdx.x & 3) * 16;

    #pragma unroll
    for (int i = 0; i < 4; ++i) {
        const float4 v = *(const float4*)(src + (size_t)(k0 + r) * 512 + n0 + c0 + i * 4);
        *(float4*)&T[r][c0 + i * 4] = v;
    }
    __syncthreads();

    // write out-row n = n0 + r, k chunk c0..c0+15 (transposed read from LDS)
    unsigned int hw[8], lw[8];
    #pragma unroll
    for (int i = 0; i < 16; i += 2) {
        const float a = T[c0 + i][r];
        const float b = T[c0 + i + 1][r];
        const unsigned int ha = hi_bits(a), la = lo_rbits(a, ha);
        const unsigned int hbv = hi_bits(b), lb = lo_rbits(b, hbv);
        hw[i >> 1] = (ha >> 16) | hbv;
        lw[i >> 1] = (la >> 16) | (lb & 0xFFFF0000u);
    }
    const size_t o = (size_t)m * 262144 + (size_t)(n0 + r) * 512 + k0 + c0;
    *(int4*)(Whi + o)     = *(int4*)&hw[0];
    *(int4*)(Whi + o + 8) = *(int4*)&hw[4];
    *(int4*)(Wlo + o)     = *(int4*)&lw[0];
    *(int4*)(Wlo + o + 8) = *(int4*)&lw[4];
}

// ---------------------------------------------------------------------------
// proj: Q|K|V = X[M,512] @ W[512,512] via 3xBF16-split MFMA (Ah*Bh+Ah*Bl+Al*Bh)
// 128x128 tile, BK=32, 256 thr = 4 waves (2x2), 64x64 per wave.
// Linear LDS [128][32] shorts (bank-balanced, analyzed). Fused col-norm2.
// XCD-chunked remap: a panel's 12 column/matrix variants stay on one XCD's L2.
// ---------------------------------------------------------------------------
__global__ __launch_bounds__(256)
void proj_mfma(const float* __restrict__ X,
               const unsigned short* __restrict__ Whi,
               const unsigned short* __restrict__ Wlo,
               float* __restrict__ Q, float* __restrict__ K, float* __restrict__ V,
               float* __restrict__ norm2q, float* __restrict__ norm2k)
{
    const int D = blockIdx.x;
    const int xcd = D & 7;
    const int slot = D >> 3;             // 0..1535
    const int v = slot % 12;             // variant: 0..11
    const int p = (slot / 12) * 8 + xcd; // row panel 0..1023
    const int z = v >> 2;                // 0=q 1=k 2=v
    const int col0 = (v & 3) * 128;
    const int row0 = p * 128;

    const unsigned short* Wth = Whi + (size_t)z * 262144;
    const unsigned short* Wtl = Wlo + (size_t)z * 262144;
    float* Outp = (z == 0) ? Q : (z == 1) ? K : V;

    __shared__ unsigned short Ah[128 * 32], Al[128 * 32];
    __shared__ unsigned short Bh[128 * 32], Bl[128 * 32];
    __shared__ float red[128];

    const int tid = threadIdx.x;
    const int wid = tid >> 6, lane = tid & 63;
    const int wm = wid >> 1, wn = wid & 1;
    const int lr = lane & 15, ls = lane >> 4;
    const int srow = tid >> 2, sslot = tid & 3;      // staging: 4 thr/row, 8 k each

    f32x4 acc[4][4];
    #pragma unroll
    for (int i = 0; i < 4; ++i)
        #pragma unroll
        for (int j = 0; j < 4; ++j) acc[i][j] = 0.0f;

    for (int k0 = 0; k0 < 512; k0 += 32) {
        // ---- stage A: f32 -> hi/lo bf16, rows srow & srow+64 ----
        #pragma unroll
        for (int rr = 0; rr < 2; ++rr) {
            const int r = srow + rr * 64;
            const float* xp = X + (size_t)(row0 + r) * 512 + k0 + sslot * 8;
            const float4 x0 = *(const float4*)xp;
            const float4 x1 = *(const float4*)(xp + 4);
            const float xs[8] = {x0.x, x0.y, x0.z, x0.w, x1.x, x1.y, x1.z, x1.w};
            unsigned int hb[8], lb[8];
            #pragma unroll
            for (int e = 0; e < 8; ++e) {
                hb[e] = hi_bits(xs[e]);
                lb[e] = lo_rbits(xs[e], hb[e]);
            }
            int4 hv = { (int)((hb[0] >> 16) | hb[1]), (int)((hb[2] >> 16) | hb[3]),
                        (int)((hb[4] >> 16) | hb[5]), (int)((hb[6] >> 16) | hb[7]) };
            int4 lv = { (int)((lb[0] >> 16) | (lb[1] & 0xFFFF0000u)),
                        (int)((lb[2] >> 16) | (lb[3] & 0xFFFF0000u)),
                        (int)((lb[4] >> 16) | (lb[5] & 0xFFFF0000u)),
                        (int)((lb[6] >> 16) | (lb[7] & 0xFFFF0000u)) };
            *(int4*)&Ah[r * 32 + sslot * 8] = hv;
            *(int4*)&Al[r * 32 + sslot * 8] = lv;
        }
        // ---- stage B: pre-split bf16, direct 16B copies ----
        #pragma unroll
        for (int rr = 0; rr < 2; ++rr) {
            const int n = srow + rr * 64;
            const size_t wo = (size_t)(col0 + n) * 512 + k0 + sslot * 8;
            *(int4*)&Bh[n * 32 + sslot * 8] = *(const int4*)(Wth + wo);
            *(int4*)&Bl[n * 32 + sslot * 8] = *(const int4*)(Wtl + wo);
        }
        __syncthreads();

        // ---- fragments + 48 MFMA ----
        short8v bh[4], bl[4];
        #pragma unroll
        for (int fn = 0; fn < 4; ++fn) {
            const int br = wn * 64 + fn * 16 + lr;
            bh[fn] = *(const short8v*)&Bh[br * 32 + ls * 8];
            bl[fn] = *(const short8v*)&Bl[br * 32 + ls * 8];
        }
        #pragma unroll
        for (int fm = 0; fm < 4; ++fm) {
            const int ar = wm * 64 + fm * 16 + lr;
            const short8v ah = *(const short8v*)&Ah[ar * 32 + ls * 8];
            const short8v al = *(const short8v*)&Al[ar * 32 + ls * 8];
            #pragma unroll
            for (int fn = 0; fn < 4; ++fn)
                acc[fm][fn] = __builtin_amdgcn_mfma_f32_16x16x32_bf16(ah, bh[fn], acc[fm][fn], 0, 0, 0);
            #pragma unroll
            for (int fn = 0; fn < 4; ++fn)
                acc[fm][fn] = __builtin_amdgcn_mfma_f32_16x16x32_bf16(ah, bl[fn], acc[fm][fn], 0, 0, 0);
            #pragma unroll
            for (int fn = 0; fn < 4; ++fn)
                acc[fm][fn] = __builtin_amdgcn_mfma_f32_16x16x32_bf16(al, bh[fn], acc[fm][fn], 0, 0, 0);
        }
        __syncthreads();
    }

    // ---- epilogue: C/D layout col=lane&15, row=(lane>>4)*4+r (m89-verified) ----
    #pragma unroll
    for (int fm = 0; fm < 4; ++fm)
        #pragma unroll
        for (int fn = 0; fn < 4; ++fn) {
            const int col = col0 + wn * 64 + fn * 16 + lr;
            #pragma unroll
            for (int r = 0; r < 4; ++r) {
                const int row = row0 + wm * 64 + fm * 16 + ls * 4 + r;
                Outp[(size_t)row * 512 + col] = acc[fm][fn][r];
            }
        }

    // ---- fused column sum-of-squares for the token-dim l2norm (Q,K only) ----
    if (z < 2) {
        if (tid < 128) red[tid] = 0.f;
        __syncthreads();
        #pragma unroll
        for (int fn = 0; fn < 4; ++fn) {
            float ss = 0.f;
            #pragma unroll
            for (int fm = 0; fm < 4; ++fm)
                #pragma unroll
                for (int r = 0; r < 4; ++r) ss += acc[fm][fn][r] * acc[fm][fn][r];
            atomicAdd(&red[wn * 64 + fn * 16 + lr], ss);
        }
        __syncthreads();
        if (tid < 128) {
            float* nrm = (z == 0) ? norm2q : norm2k;
            atomicAdd(&nrm[(row0 / NTOK) * CDIM + col0 + tid], red[tid]);
        }
    }
}

// ---------------------------------------------------------------------------
// out = Tmp(hi/lo bf16)[M,512] @ Wp^T-split + bp  (A pre-split by apply_attn)
// ---------------------------------------------------------------------------
__global__ __launch_bounds__(256)
void out_mfma(const unsigned short* __restrict__ Thi,
              const unsigned short* __restrict__ Tlo,
              const unsigned short* __restrict__ Whi,
              const unsigned short* __restrict__ Wlo,
              const float* __restrict__ bias, float* __restrict__ Out)
{
    const int D = blockIdx.x;
    const int xcd = D & 7;
    const int slot = D >> 3;              // 0..511
    const int v = slot & 3;
    const int p = (slot >> 2) * 8 + xcd;  // 0..1023
    const int col0 = v * 128;
    const int row0 = p * 128;

    const unsigned short* Wth = Whi + (size_t)3 * 262144;   // Wp^T slot
    const unsigned short* Wtl = Wlo + (size_t)3 * 262144;

    __shared__ unsigned short Ah[128 * 32], Al[128 * 32];
    __shared__ unsigned short Bh[128 * 32], Bl[128 * 32];

    const int tid = threadIdx.x;
    const int wid = tid >> 6, lane = tid & 63;
    const int wm = wid >> 1, wn = wid & 1;
    const int lr = lane & 15, ls = lane >> 4;
    const int srow = tid >> 2, sslot = tid & 3;

    f32x4 acc[4][4];
    #pragma unroll
    for (int i = 0; i < 4; ++i)
        #pragma unroll
        for (int j = 0; j < 4; ++j) acc[i][j] = 0.0f;

    for (int k0 = 0; k0 < 512; k0 += 32) {
        #pragma unroll
        for (int rr = 0; rr < 2; ++rr) {
            const int r = srow + rr * 64;
            const size_t ao = (size_t)(row0 + r) * 512 + k0 + sslot * 8;
            *(int4*)&Ah[r * 32 + sslot * 8] = *(const int4*)(Thi + ao);
            *(int4*)&Al[r * 32 + sslot * 8] = *(const int4*)(Tlo + ao);
        }
        #pragma unroll
        for (int rr = 0; rr < 2; ++rr) {
            const int n = srow + rr * 64;
            const size_t wo = (size_t)(col0 + n) * 512 + k0 + sslot * 8;
            *(int4*)&Bh[n * 32 + sslot * 8] = *(const int4*)(Wth + wo);
            *(int4*)&Bl[n * 32 + sslot * 8] = *(const int4*)(Wtl + wo);
        }
        __syncthreads();

        short8v bh[4], bl[4];
        #pragma unroll
        for (int fn = 0; fn < 4; ++fn) {
            const int br = wn * 64 + fn * 16 + lr;
            bh[fn] = *(const short8v*)&Bh[br * 32 + ls * 8];
            bl[fn] = *(const short8v*)&Bl[br * 32 + ls * 8];
        }
        #pragma unroll
        for (int fm = 0; fm < 4; ++fm) {
            const int ar = wm * 64 + fm * 16 + lr;
            const short8v ah = *(const short8v*)&Ah[ar * 32 + ls * 8];
            const short8v al = *(const short8v*)&Al[ar * 32 + ls * 8];
            #pragma unroll
            for (int fn = 0; fn < 4; ++fn)
                acc[fm][fn] = __builtin_amdgcn_mfma_f32_16x16x32_bf16(ah, bh[fn], acc[fm][fn], 0, 0, 0);
            #pragma unroll
            for (int fn = 0; fn < 4; ++fn)
                acc[fm][fn] = __builtin_amdgcn_mfma_f32_16x16x32_bf16(ah, bl[fn], acc[fm][fn], 0, 0, 0);
            #pragma unroll
            for (int fn = 0; fn < 4; ++fn)
                acc[fm][fn] = __builtin_amdgcn_mfma_f32_16x16x32_bf16(al, bh[fn], acc[fm][fn], 0, 0, 0);
        }
        __syncthreads();
    }

    #pragma unroll
    for (int fm = 0; fm < 4; ++fm)
        #pragma unroll
        for (int fn = 0; fn < 4; ++fn) {
            const int col = col0 + wn * 64 + fn * 16 + lr;
            const float bv = bias[col];
            #pragma unroll
            for (int r = 0; r < 4; ++r) {
                const int row = row0 + wm * 64 + fm * 16 + ls * 4 + r;
                Out[(size_t)row * 512 + col] = acc[fm][fn][r] + bv;
            }
        }
}

// ---------------------------------------------------------------------------
// G[b,h,d,e] = sum_n K[b,n,h*64+d] * Q[b,n,h*64+e]   (f32, atomically chunked)
// ---------------------------------------------------------------------------
__global__ __launch_bounds__(256)
void kq_gram(const float* __restrict__ Q, const float* __restrict__ K,
             float* __restrict__ G)
{
    const int h = blockIdx.y, b = blockIdx.z;
    const int n0 = blockIdx.x * 1024;
    __shared__ float Ks[8][68];
    __shared__ float Qs[8][68];
    const int tid = threadIdx.x;
    const int td = tid >> 4;
    const int te = tid & 15;

    float acc[4][4];
    #pragma unroll
    for (int i = 0; i < 4; ++i)
        #pragma unroll
        for (int j = 0; j < 4; ++j) acc[i][j] = 0.f;

    const size_t base = ((size_t)b * NTOK + n0) * CDIM + h * 64;
    const int ln = tid >> 5;
    const int lc = (tid & 31) * 2;

    for (int ns = 0; ns < 1024; ns += 8) {
        const size_t a = base + (size_t)(ns + ln) * CDIM + lc;
        *(float2*)&Ks[ln][lc] = *(const float2*)(K + a);
        *(float2*)&Qs[ln][lc] = *(const float2*)(Q + a);
        __syncthreads();
        #pragma unroll
        for (int nn = 0; nn < 8; ++nn) {
            float4 av = *(const float4*)&Ks[nn][td * 4];
            float4 bv = *(const float4*)&Qs[nn][te * 4];
            float a4[4] = {av.x, av.y, av.z, av.w};
            float b4[4] = {bv.x, bv.y, bv.z, bv.w};
            #pragma unroll
            for (int i = 0; i < 4; ++i)
                #pragma unroll
                for (int j = 0; j < 4; ++j)
                    acc[i][j] += a4[i] * b4[j];
        }
        __syncthreads();
    }

    float* Gbh = G + ((size_t)(b * NHEADS + h)) * 64 * 64;
    #pragma unroll
    for (int i = 0; i < 4; ++i)
        #pragma unroll
        for (int j = 0; j < 4; ++j)
            atomicAdd(&Gbh[(td * 4 + i) * 64 + te * 4 + j], acc[i][j]);
}

// ---------------------------------------------------------------------------
// attn row softmax with fused l2-normalization: logits are cosine sims (<=1)
// ---------------------------------------------------------------------------
__global__ __launch_bounds__(64)
void attn_softmax(const float* __restrict__ G, const float* __restrict__ norm2q,
                  const float* __restrict__ norm2k, const float* __restrict__ rescale,
                  float* __restrict__ A)
{
    const int row = blockIdx.x;              // (b*NHEADS+h)*64 + d
    const int e = threadIdx.x;
    const int d = row & 63;
    const int bh = row >> 6;
    const int h = bh & (NHEADS - 1);
    const int b = bh >> 3;
    const float nk = fmaxf(sqrtf(norm2k[b * CDIM + h * 64 + d]), 1e-12f);
    const float nq = fmaxf(sqrtf(norm2q[b * CDIM + h * 64 + e]), 1e-12f);
    float val = G[(size_t)row * 64 + e] / (nk * nq) * rescale[h];

    float m = val;
    #pragma unroll
    for (int off = 32; off; off >>= 1) m = fmaxf(m, __shfl_xor(m, off));
    float ex = expf(val - m);
    float s = ex;
    #pragma unroll
    for (int off = 32; off; off >>= 1) s += __shfl_xor(s, off);
    A[(size_t)row * 64 + e] = ex / s;
}

// ---------------------------------------------------------------------------
// Tmp{hi,lo}[b,n,h*64+d] = bf16split( sum_e attn[d,e] * V[n,e]*illu[n,e] )
// ---------------------------------------------------------------------------
__global__ __launch_bounds__(256)
void apply_attn(const float* __restrict__ A, const float* __restrict__ Vinp,
                const float* __restrict__ illu,
                unsigned short* __restrict__ Thi, unsigned short* __restrict__ Tlo)
{
    const int h = blockIdx.y, b = blockIdx.z;
    const int n0 = blockIdx.x * 64;
    __shared__ float As[64][68];   // attn[d][e]
    __shared__ float Vs[64][68];   // token x e (V*illu)

    const float* Ahp = A + ((size_t)(b * NHEADS + h)) * 4096;
    for (int i = threadIdx.x; i < 1024; i += 256) {
        float4 v = *(const float4*)(Ahp + i * 4);
        *(float4*)&As[i >> 4][(i & 15) * 4] = v;
    }
    const size_t base = ((size_t)b * NTOK + n0) * CDIM + h * 64;
    for (int i = threadIdx.x; i < 1024; i += 256) {
        const int tk = i >> 4, eq = (i & 15) * 4;
        const size_t a = base + (size_t)tk * CDIM + eq;
        float4 v = *(const float4*)(Vinp + a);
        float4 f = *(const float4*)(illu + a);
        float4 r = {v.x * f.x, v.y * f.y, v.z * f.z, v.w * f.w};
        *(float4*)&Vs[tk][eq] = r;
    }
    __syncthreads();

    const int tk = threadIdx.x >> 2;
    const int db = (threadIdx.x & 3) * 16;
    float o[16];
    #pragma unroll
    for (int i = 0; i < 16; ++i) o[i] = 0.f;
    for (int e = 0; e < 64; e += 4) {
        const float4 vv = *(const float4*)&Vs[tk][e];
        #pragma unroll
        for (int i = 0; i < 16; ++i) {
            const float4 a = *(const float4*)&As[db + i][e];
            o[i] += a.x * vv.x + a.y * vv.y + a.z * vv.z + a.w * vv.w;
        }
    }
    const size_t ob = base + (size_t)tk * CDIM + db;
    #pragma unroll
    for (int i = 0; i < 16; i += 2) {
        const unsigned int h0 = hi_bits(o[i]),     l0 = lo_rbits(o[i], h0);
        const unsigned int h1 = hi_bits(o[i + 1]), l1 = lo_rbits(o[i + 1], h1);
        *(unsigned int*)(Thi + ob + i) = (h0 >> 16) | h1;
        *(unsigned int*)(Tlo + ob + i) = (l0 >> 16) | (l1 & 0xFFFF0000u);
    }
}

// ---------------------------------------------------------------------------
// Depthwise 3x3 SAME, NHWC. MODE 0: out = gelu_exact(conv(in)); MODE 1: out += conv(in)
// L2 absorbs the 9x neighborhood re-reads (3 rows = 1.5 MB << 4 MB/XCD).
// ---------------------------------------------------------------------------
template <int MODE>
__global__ __launch_bounds__(256)
void dwconv3x3(const float* __restrict__ In, const float* __restrict__ Kw,
               float* __restrict__ Out)
{
    __shared__ float Kws[9][CDIM];
    for (int i = threadIdx.x; i < 9 * CDIM; i += 256) {
        const int c = i / 9, tap = i % 9;
        Kws[tap][c] = Kw[i];
    }
    __syncthreads();

    const int pix = blockIdx.x * 2 + (threadIdx.x >> 7);
    const int cq = (threadIdx.x & 127) * 4;
    const int b = pix / (HH * WW);
    const int yx = pix % (HH * WW);
    const int y = yx / WW, x = yx % WW;

    float4 acc = {0.f, 0.f, 0.f, 0.f};
    #pragma unroll
    for (int ky = 0; ky < 3; ++ky) {
        const int yy = y + ky - 1;
        if (yy < 0 || yy >= HH) continue;
        #pragma unroll
        for (int kx = 0; kx < 3; ++kx) {
            const int xx = x + kx - 1;
            if (xx < 0 || xx >= WW) continue;
            const float4 v = *(const float4*)(
                In + (((size_t)b * HH + yy) * WW + xx) * CDIM + cq);
            const float4 w = *(const float4*)&Kws[ky * 3 + kx][cq];
            acc.x += w.x * v.x; acc.y += w.y * v.y;
            acc.z += w.z * v.z; acc.w += w.w * v.w;
        }
    }

    float* op = Out + ((size_t)pix) * CDIM + cq;
    if (MODE == 0) {
        const float inv_sqrt2 = 0.70710678118654752f;
        float4 g;
        g.x = 0.5f * acc.x * (1.f + erff(acc.x * inv_sqrt2));
        g.y = 0.5f * acc.y * (1.f + erff(acc.y * inv_sqrt2));
        g.z = 0.5f * acc.z * (1.f + erff(acc.z * inv_sqrt2));
        g.w = 0.5f * acc.w * (1.f + erff(acc.w * inv_sqrt2));
        *(float4*)op = g;
    } else {
        float4 cur = *(const float4*)op;
        cur.x += acc.x; cur.y += acc.y; cur.z += acc.z; cur.w += acc.w;
        *(float4*)op = cur;
    }
}

// ---------------------------------------------------------------------------
extern "C" void kernel_launch(void* const* d_in, const int* in_sizes, int n_in,
                              void* d_out, int out_size, void* d_ws, size_t ws_size,
                              hipStream_t stream)
{
    (void)in_sizes; (void)n_in; (void)out_size; (void)ws_size;
    const float* x_in    = (const float*)d_in[0];
    const float* illu    = (const float*)d_in[1];
    const float* Wq      = (const float*)d_in[2];
    const float* Wk      = (const float*)d_in[3];
    const float* Wv      = (const float*)d_in[4];
    const float* rescale = (const float*)d_in[5];
    const float* Wp      = (const float*)d_in[6];
    const float* bp      = (const float*)d_in[7];
    const float* conv1   = (const float*)d_in[8];
    const float* conv2   = (const float*)d_in[9];
    float* out = (float*)d_out;

    const size_t NELEM = (size_t)MROWS * CDIM;   // 67108864
    char* ws = (char*)d_ws;
    float* Q = (float*)ws;                                  // 256 MB
    float* K = (float*)(ws + NELEM * 4);                    // 256 MB
    float* V = (float*)(ws + NELEM * 8);                    // 256 MB
    unsigned short* Whi = (unsigned short*)(ws + NELEM * 12);         // 2 MB
    unsigned short* Wlo = (unsigned short*)((char*)Whi + 2097152);    // 2 MB
    float* n2q  = (float*)((char*)Wlo + 2097152);           // 1024 f32
    float* n2k  = n2q + 1024;
    float* G    = n2k + 1024;                               // 65536 f32
    // overlays (producer regions dead by then):
    float* Attn = G + 65536;                                // 65536 f32
    unsigned short* Thi = (unsigned short*)Q;               // 128 MB (Q dead after gram)
    unsigned short* Tlo = (unsigned short*)(ws + NELEM * 2);// 128 MB (2nd half of Q)
    float* Pos1 = K;                                        // 256 MB (K dead after gram)

    // zero atomic accumulators: n2q + n2k + G contiguous
    hipMemsetAsync(n2q, 0, (1024 + 1024 + 65536) * sizeof(float), stream);

    wsplit<<<dim3(8, 8, 4), 256, 0, stream>>>(Wq, Wk, Wv, Wp, Whi, Wlo);

    proj_mfma<<<12288, 256, 0, stream>>>(x_in, Whi, Wlo, Q, K, V, n2q, n2k);

    kq_gram<<<dim3(64, NHEADS, BATCH), 256, 0, stream>>>(Q, K, G);

    attn_softmax<<<BATCH * NHEADS * 64, 64, 0, stream>>>(G, n2q, n2k, rescale, Attn);

    apply_attn<<<dim3(NTOK / 64, NHEADS, BATCH), 256, 0, stream>>>(
        Attn, V, illu, Thi, Tlo);

    out_mfma<<<4096, 256, 0, stream>>>(Thi, Tlo, Whi, Wlo, bp, out);

    dwconv3x3<0><<<BATCH * HH * WW / 2, 256, 0, stream>>>(V, conv1, Pos1);
    dwconv3x3<1><<<BATCH * HH * WW / 2, 256, 0, stream>>>(Pos1, conv2, out);
}